// Round 8
// baseline (347.356 us; speedup 1.0000x reference)
//
#include <hip/hip_runtime.h>
#include <hip/hip_cooperative_groups.h>

namespace cg = cooperative_groups;

constexpr int Bdim = 8192;
constexpr int Ddim = 256;
constexpr int NBLK = 1024;                  // 4 blocks/CU, all co-resident
constexpr float MARGIN_F = 0.1f;

typedef int iv4 __attribute__((ext_vector_type(4)));

// Process one row's suffix j in [r+1, 8192) with the whole 256-thread block.
__device__ __forceinline__ void row_seg(int r, const float* __restrict__ d,
                                        const int* __restrict__ cmp,
                                        int tid, float& s, int& cnt) {
    float dr = d[r];
    int jbeg = r + 1;
    int abeg = (jbeg + 3) & ~3;              // first 16B-aligned column
    int nh   = abeg - jbeg;                  // 0..3 scalar head elements
    if (tid < nh) {
        int j = jbeg + tid;
        int c = cmp[(size_t)r * Bdim + j];
        if (c != 0) {
            float x = fmaf((float)c, d[j] - dr, MARGIN_F);
            s += fmaxf(x, 0.0f); cnt += 1;
        }
    }
    int nq = (Bdim - abeg) >> 2;             // int4 quads in the row
    const iv4*    pv = (const iv4*)(cmp + (size_t)r * Bdim + abeg);
    const float4* dv = (const float4*)(d + abeg);

    int q = tid;
    for (; q + 256 < nq; q += 512) {         // 2-deep: keep 2 loads in flight
        iv4 c0 = pv[q];       float4 dj0 = dv[q];
        iv4 c1 = pv[q + 256]; float4 dj1 = dv[q + 256];
        { bool a = c0.x != 0; float x = fmaf((float)c0.x, dj0.x - dr, MARGIN_F);
          s += a ? fmaxf(x, 0.0f) : 0.0f; cnt += a ? 1 : 0; }
        { bool a = c0.y != 0; float x = fmaf((float)c0.y, dj0.y - dr, MARGIN_F);
          s += a ? fmaxf(x, 0.0f) : 0.0f; cnt += a ? 1 : 0; }
        { bool a = c0.z != 0; float x = fmaf((float)c0.z, dj0.z - dr, MARGIN_F);
          s += a ? fmaxf(x, 0.0f) : 0.0f; cnt += a ? 1 : 0; }
        { bool a = c0.w != 0; float x = fmaf((float)c0.w, dj0.w - dr, MARGIN_F);
          s += a ? fmaxf(x, 0.0f) : 0.0f; cnt += a ? 1 : 0; }
        { bool a = c1.x != 0; float x = fmaf((float)c1.x, dj1.x - dr, MARGIN_F);
          s += a ? fmaxf(x, 0.0f) : 0.0f; cnt += a ? 1 : 0; }
        { bool a = c1.y != 0; float x = fmaf((float)c1.y, dj1.y - dr, MARGIN_F);
          s += a ? fmaxf(x, 0.0f) : 0.0f; cnt += a ? 1 : 0; }
        { bool a = c1.z != 0; float x = fmaf((float)c1.z, dj1.z - dr, MARGIN_F);
          s += a ? fmaxf(x, 0.0f) : 0.0f; cnt += a ? 1 : 0; }
        { bool a = c1.w != 0; float x = fmaf((float)c1.w, dj1.w - dr, MARGIN_F);
          s += a ? fmaxf(x, 0.0f) : 0.0f; cnt += a ? 1 : 0; }
    }
    for (; q < nq; q += 256) {
        iv4 c = pv[q]; float4 dj = dv[q];
        { bool a = c.x != 0; float x = fmaf((float)c.x, dj.x - dr, MARGIN_F);
          s += a ? fmaxf(x, 0.0f) : 0.0f; cnt += a ? 1 : 0; }
        { bool a = c.y != 0; float x = fmaf((float)c.y, dj.y - dr, MARGIN_F);
          s += a ? fmaxf(x, 0.0f) : 0.0f; cnt += a ? 1 : 0; }
        { bool a = c.z != 0; float x = fmaf((float)c.z, dj.z - dr, MARGIN_F);
          s += a ? fmaxf(x, 0.0f) : 0.0f; cnt += a ? 1 : 0; }
        { bool a = c.w != 0; float x = fmaf((float)c.w, dj.w - dr, MARGIN_F);
          s += a ? fmaxf(x, 0.0f) : 0.0f; cnt += a ? 1 : 0; }
    }
}

// Single cooperative kernel: norms -> grid sync -> pairs -> grid sync ->
// block 0 final reduce. Removes 2 kernel-boundary gaps + the single-block
// k_final launch tail. Row-paired triangle partition (R7), 4 virtual rows
// per block.
__global__ __launch_bounds__(256, 4) void k_all(const float* __restrict__ emb,
                                                const int* __restrict__ cmp,
                                                float* __restrict__ d,
                                                double* __restrict__ psum,
                                                unsigned int* __restrict__ pcnt,
                                                float* __restrict__ out) {
    int tid  = threadIdx.x;
    int lane = tid & 63;
    int wave = tid >> 6;

    // ---- Phase 1: hyperbolic norms, 8 rows per block (2 per wave) ----
#pragma unroll
    for (int h = 0; h < 2; ++h) {
        int row = blockIdx.x * 8 + wave * 2 + h;
        float4 v = ((const float4*)(emb + (size_t)row * Ddim))[lane];
        float s = v.x * v.x + v.y * v.y + v.z * v.z + v.w * v.w;
#pragma unroll
        for (int off = 32; off > 0; off >>= 1) s += __shfl_down(s, off, 64);
        if (lane == 0) {
            float n = fminf(sqrtf(s), 1.0f - 1e-5f);
            d[row] = logf((1.0f + n) / (1.0f - n));
        }
    }
    cg::this_grid().sync();

    // ---- Phase 2: pair loss over row-paired triangle partition ----
    float s = 0.0f;
    int cnt = 0;
#pragma unroll
    for (int h = 0; h < 4; ++h) {
        int v  = blockIdx.x * 4 + h;         // 0..4095
        int r0 = v;
        int r1 = 8190 - v;
        row_seg(r0, d, cmp, tid, s, cnt);
        if (r1 != r0) row_seg(r1, d, cmp, tid, s, cnt);
    }

#pragma unroll
    for (int off = 32; off > 0; off >>= 1) {
        s   += __shfl_down(s, off, 64);
        cnt += __shfl_down(cnt, off, 64);
    }
    __shared__ float ws_s[4];
    __shared__ int   ws_c[4];
    if ((tid & 63) == 0) { ws_s[wave] = s; ws_c[wave] = cnt; }
    __syncthreads();
    if (tid == 0) {
        float st = ws_s[0] + ws_s[1] + ws_s[2] + ws_s[3];
        int   ct = ws_c[0] + ws_c[1] + ws_c[2] + ws_c[3];
        psum[blockIdx.x] = (double)st;
        pcnt[blockIdx.x] = (unsigned int)ct;
    }
    __threadfence();
    cg::this_grid().sync();

    // ---- Phase 3: block 0 reduces the 1024 partials ----
    if (blockIdx.x == 0) {
        double sd_ = 0.0;
        unsigned long long cc = 0;
        for (int idx = tid; idx < NBLK; idx += 256) {
            sd_ += psum[idx];
            cc  += pcnt[idx];
        }
#pragma unroll
        for (int off = 32; off > 0; off >>= 1) {
            sd_ += __shfl_down(sd_, off, 64);
            cc  += __shfl_down(cc, off, 64);
        }
        __shared__ double rd[4];
        __shared__ unsigned long long rc[4];
        if ((tid & 63) == 0) { rd[wave] = sd_; rc[wave] = cc; }
        __syncthreads();
        if (tid == 0) {
            double st = rd[0] + rd[1] + rd[2] + rd[3];
            unsigned long long ct = rc[0] + rc[1] + rc[2] + rc[3];
            out[0] = (ct > 0) ? (float)(st / (double)ct) : 0.0f;
        }
    }
}

extern "C" void kernel_launch(void* const* d_in, const int* in_sizes, int n_in,
                              void* d_out, int out_size, void* d_ws, size_t ws_size,
                              hipStream_t stream) {
    const float* emb = (const float*)d_in[0];
    const int*   cmp = (const int*)d_in[1];
    float* out = (float*)d_out;

    char* ws = (char*)d_ws;
    float*        dvec = (float*)ws;                              // 8192 * 4 B
    double*       psum = (double*)(ws + 32768);                   // 1024 * 8 B
    unsigned int* pcnt = (unsigned int*)(ws + 32768 + NBLK * 8);  // 1024 * 4 B

    void* args[] = {(void*)&emb, (void*)&cmp, (void*)&dvec,
                    (void*)&psum, (void*)&pcnt, (void*)&out};
    hipLaunchCooperativeKernel((const void*)k_all, dim3(NBLK), dim3(256),
                               args, 0, stream);
}

// Round 9
// 35.769 us; speedup vs baseline: 9.7111x; 9.7111x over previous
//
#include <hip/hip_runtime.h>

constexpr int Bdim = 8192;
constexpr int Ddim = 256;
constexpr int TS   = 512;                   // tile side (square tiles)
constexpr int NTt  = Bdim / TS;             // 16 tiles per side
constexpr int NTRI = NTt * (NTt + 1) / 2;   // 136 upper-tri tiles
constexpr int RPU  = 16;                    // rows per unit
constexpr int CPT  = TS / RPU;              // 32 chunks per tile
constexpr int NUNIT = NTRI * CPT;           // 4352 units
constexpr int NBLK  = 2048;
constexpr int RPW   = RPU / 4;              // 4 rows per wave
constexpr float MARGIN_F = 0.1f;

typedef int iv4 __attribute__((ext_vector_type(4)));

// d(x,0) = 2*artanh(||x||) = log((1+n)/(1-n)), one wave per row
__global__ __launch_bounds__(256) void k_norm(const float* __restrict__ emb,
                                              float* __restrict__ d) {
    int row  = blockIdx.x * 4 + (threadIdx.x >> 6);
    int lane = threadIdx.x & 63;
    float4 v = ((const float4*)(emb + (size_t)row * Ddim))[lane];
    float s = v.x * v.x + v.y * v.y + v.z * v.z + v.w * v.w;
#pragma unroll
    for (int off = 32; off > 0; off >>= 1) s += __shfl_down(s, off, 64);
    if (lane == 0) {
        float n = fminf(sqrtf(s), 1.0f - 1e-5f);
        d[row] = logf((1.0f + n) / (1.0f - n));
    }
}

// Interior element: s += relu(fma(c, dj-di, m)) unconditionally (c==0
// contributes exactly 0.1f, corrected later); cnt += c&1 (c in {-1,0,1}).
#define ACCE(cv, djv, div)                                    \
    {                                                         \
        float x = fmaf((float)(cv), (djv) - (div), MARGIN_F); \
        s += fmaxf(x, 0.0f);                                  \
        cntA += (cv) & 1;                                     \
    }

__global__ __launch_bounds__(256) void k_pairs(const float* __restrict__ d,
                                               const int* __restrict__ cmp,
                                               double* __restrict__ psum,
                                               unsigned int* __restrict__ pcnt) {
    int tid  = threadIdx.x;
    int lane = tid & 63;
    int wave = tid >> 6;

    float s = 0.0f;      // includes +0.1 per interior zero (corrected at end)
    int cntA = 0;        // interior nonzeros
    int cntB = 0;        // diagonal-path nonzeros
    int nproc = 0;       // interior elements processed (for correction)

    for (int u = blockIdx.x; u < NUNIT; u += NBLK) {
        int tri   = u % NTRI;
        int chunk = u / NTRI;
        int rem = tri, ti = 0;
        while (rem >= NTt - ti) { rem -= NTt - ti; ++ti; }
        int tj = ti + rem;

        int i0 = ti * TS + chunk * RPU + wave * RPW;   // this wave's 4 rows
        int j0 = tj * TS + lane * 4;
        int j1 = j0 + 256;
        float4 dj0 = *(const float4*)(d + j0);
        float4 dj1 = *(const float4*)(d + j1);
        const iv4* p = (const iv4*)(cmp + (size_t)i0 * Bdim + j0);

        if (ti == tj) {
            // diagonal tile: masked per-element path (no margin trick)
#pragma unroll
            for (int r = 0; r < RPW; ++r) {
                int   i  = i0 + r;
                float di = d[i];
                const iv4* pr = p + (size_t)r * (Bdim / 4);
                if (j0 + 3 > i) {
                    iv4 c = pr[0];
                    { bool a = (c.x != 0) & (j0 + 0 > i);
                      float x = fmaf((float)c.x, dj0.x - di, MARGIN_F);
                      s += a ? fmaxf(x, 0.0f) : 0.0f; cntB += a ? 1 : 0; }
                    { bool a = (c.y != 0) & (j0 + 1 > i);
                      float x = fmaf((float)c.y, dj0.y - di, MARGIN_F);
                      s += a ? fmaxf(x, 0.0f) : 0.0f; cntB += a ? 1 : 0; }
                    { bool a = (c.z != 0) & (j0 + 2 > i);
                      float x = fmaf((float)c.z, dj0.z - di, MARGIN_F);
                      s += a ? fmaxf(x, 0.0f) : 0.0f; cntB += a ? 1 : 0; }
                    { bool a = (c.w != 0) & (j0 + 3 > i);
                      float x = fmaf((float)c.w, dj0.w - di, MARGIN_F);
                      s += a ? fmaxf(x, 0.0f) : 0.0f; cntB += a ? 1 : 0; }
                }
                if (j1 + 3 > i) {
                    iv4 c = pr[64];
                    { bool a = (c.x != 0) & (j1 + 0 > i);
                      float x = fmaf((float)c.x, dj1.x - di, MARGIN_F);
                      s += a ? fmaxf(x, 0.0f) : 0.0f; cntB += a ? 1 : 0; }
                    { bool a = (c.y != 0) & (j1 + 1 > i);
                      float x = fmaf((float)c.y, dj1.y - di, MARGIN_F);
                      s += a ? fmaxf(x, 0.0f) : 0.0f; cntB += a ? 1 : 0; }
                    { bool a = (c.z != 0) & (j1 + 2 > i);
                      float x = fmaf((float)c.z, dj1.z - di, MARGIN_F);
                      s += a ? fmaxf(x, 0.0f) : 0.0f; cntB += a ? 1 : 0; }
                    { bool a = (c.w != 0) & (j1 + 3 > i);
                      float x = fmaf((float)c.w, dj1.w - di, MARGIN_F);
                      s += a ? fmaxf(x, 0.0f) : 0.0f; cntB += a ? 1 : 0; }
                }
            }
        } else {
            // interior: batch all 8 loads (4 rows x 2 windows), then compute
            iv4 c0[RPW], c1[RPW];
            float di[RPW];
#pragma unroll
            for (int r = 0; r < RPW; ++r) {
                const iv4* pr = p + (size_t)r * (Bdim / 4);
                c0[r] = pr[0];
                c1[r] = pr[64];
            }
#pragma unroll
            for (int r = 0; r < RPW; ++r) di[r] = d[i0 + r];
#pragma unroll
            for (int r = 0; r < RPW; ++r) {
                ACCE(c0[r].x, dj0.x, di[r]);
                ACCE(c0[r].y, dj0.y, di[r]);
                ACCE(c0[r].z, dj0.z, di[r]);
                ACCE(c0[r].w, dj0.w, di[r]);
                ACCE(c1[r].x, dj1.x, di[r]);
                ACCE(c1[r].y, dj1.y, di[r]);
                ACCE(c1[r].z, dj1.z, di[r]);
                ACCE(c1[r].w, dj1.w, di[r]);
            }
            nproc += 8 * RPW;
        }
    }

    // remove the 0.1 contributed by each interior zero element
    s -= MARGIN_F * (float)(nproc - cntA);
    int cnt = cntA + cntB;

#pragma unroll
    for (int off = 32; off > 0; off >>= 1) {
        s   += __shfl_down(s, off, 64);
        cnt += __shfl_down(cnt, off, 64);
    }
    __shared__ float ws_s[4];
    __shared__ int   ws_c[4];
    if ((tid & 63) == 0) { ws_s[wave] = s; ws_c[wave] = cnt; }
    __syncthreads();
    if (tid == 0) {
        float st = ws_s[0] + ws_s[1] + ws_s[2] + ws_s[3];
        int   ct = ws_c[0] + ws_c[1] + ws_c[2] + ws_c[3];
        psum[blockIdx.x] = (double)st;
        pcnt[blockIdx.x] = (unsigned int)ct;
    }
}

__global__ __launch_bounds__(256) void k_final(const double* __restrict__ psum,
                                               const unsigned int* __restrict__ pcnt,
                                               float* __restrict__ out) {
    int tid = threadIdx.x;
    double s = 0.0;
    unsigned long long c = 0;
    for (int idx = tid; idx < NBLK; idx += 256) {
        s += psum[idx];
        c += pcnt[idx];
    }
#pragma unroll
    for (int off = 32; off > 0; off >>= 1) {
        s += __shfl_down(s, off, 64);
        c += __shfl_down(c, off, 64);
    }
    __shared__ double sd[4];
    __shared__ unsigned long long sc[4];
    int wave = tid >> 6;
    if ((tid & 63) == 0) { sd[wave] = s; sc[wave] = c; }
    __syncthreads();
    if (tid == 0) {
        double st = sd[0] + sd[1] + sd[2] + sd[3];
        unsigned long long ct = sc[0] + sc[1] + sc[2] + sc[3];
        out[0] = (ct > 0) ? (float)(st / (double)ct) : 0.0f;
    }
}

extern "C" void kernel_launch(void* const* d_in, const int* in_sizes, int n_in,
                              void* d_out, int out_size, void* d_ws, size_t ws_size,
                              hipStream_t stream) {
    const float* emb = (const float*)d_in[0];
    const int*   cmp = (const int*)d_in[1];
    float* out = (float*)d_out;

    char* ws = (char*)d_ws;
    float*        dvec = (float*)ws;                              // 8192 * 4 B
    double*       psum = (double*)(ws + 32768);                   // 2048 * 8 B
    unsigned int* pcnt = (unsigned int*)(ws + 32768 + NBLK * 8);  // 2048 * 4 B

    hipLaunchKernelGGL(k_norm, dim3(Bdim / 4), dim3(256), 0, stream, emb, dvec);
    hipLaunchKernelGGL(k_pairs, dim3(NBLK), dim3(256), 0, stream,
                       dvec, cmp, psum, pcnt);
    hipLaunchKernelGGL(k_final, dim3(1), dim3(256), 0, stream, psum, pcnt, out);
}